// Round 1
// baseline (78.973 us; speedup 1.0000x reference)
//
#include <hip/hip_runtime.h>
#include <math.h>

// S4D kernel materialization:
//   out[d,l] = dt_d * sum_n Re{ (Cr + i Ci) * B * exp(dt_d * (Ar + i Ai) * l) }
// D_MODEL=1024, N_STATE=64, SEQ_LEN=1024, all fp32.
//
// Strategy: per (d,n) the l-sequence is geometric in C. Each thread owns one d
// and CHUNK=8 l-values spaced TPD=128 apart (l = t + 128*j). It computes the
// initial complex term y = w * exp(dtA * t) with transcendentals once per n,
// then advances by the precomputed per-128-steps rotation (4 FMA per step).
// Per-(d,n) constants are staged in LDS as two float4 (broadcast reads).

#define D_MODEL 1024
#define N_STATE 64
#define SEQ_LEN 1024
#define CHUNK   8
#define TPD     (SEQ_LEN / CHUNK)   // 128 threads per d row
#define DPB     2                   // d rows per block
#define BLOCK   (TPD * DPB)         // 256

#define INV_2PI 0.15915494309189535

__device__ __forceinline__ float sin_rev(float f) { return __builtin_amdgcn_sinf(f); }
__device__ __forceinline__ float cos_rev(float f) { return __builtin_amdgcn_cosf(f); }

__global__ __launch_bounds__(BLOCK) void s4d_kernel(
    const float* __restrict__ A_real, const float* __restrict__ A_imag,
    const float* __restrict__ C, const float* __restrict__ log_dt,
    const float* __restrict__ B, float* __restrict__ out)
{
  // sA = {xr, wr, wi, step_r}, sB = {step_i, rev_hi, rev_lo, pad}
  __shared__ float4 sA[DPB][N_STATE];
  __shared__ float4 sB[DPB][N_STATE];

  const int tid = threadIdx.x;

  // ---- precompute per-(d,n) constants (128 threads active) ----
  if (tid < DPB * N_STATE) {
    const int ld = tid >> 6;            // which d-row in this block
    const int n  = tid & (N_STATE - 1);
    const int d  = blockIdx.x * DPB + ld;
    const float dt = __expf(log_dt[d]);
    const float ar = A_real[d * N_STATE + n];
    const float ai = A_imag[d * N_STATE + n];
    const float b  = B[d * N_STATE + n];
    const float cr = C[(d * N_STATE + n) * 2 + 0];
    const float ci = C[(d * N_STATE + n) * 2 + 1];

    const float xr = dt * ar;                               // decay / unit l
    const double drev = (double)dt * (double)ai * INV_2PI;  // revolutions / unit l
    const float hi = (float)drev;
    const float lo = (float)(drev - (double)hi);

    // rotation for a jump of TPD l-steps: exp(dtA * TPD)
    const float  eS = __expf(xr * (float)TPD);
    const double rS = drev * (double)TPD;
    const float  fS = (float)(rS - floor(rS));
    const float str = eS * cos_rev(fS);
    const float sti = eS * sin_rev(fS);

    sA[ld][n] = make_float4(xr, cr * b * dt, ci * b * dt, str);
    sB[ld][n] = make_float4(sti, hi, lo, 0.0f);
  }
  __syncthreads();

  const int ld = tid / TPD;
  const int t  = tid % TPD;
  const int d  = blockIdx.x * DPB + ld;
  const float tf = (float)t;

  float acc[CHUNK];
  #pragma unroll
  for (int j = 0; j < CHUNK; ++j) acc[j] = 0.0f;

  #pragma unroll 2
  for (int n = 0; n < N_STATE; ++n) {
    const float4 a  = sA[ld][n];
    const float4 bv = sB[ld][n];
    const float xr = a.x, wr = a.y, wi = a.z, str = a.w;
    const float sti = bv.x, hi = bv.y, lo = bv.z;

    // phase at l = t, in revolutions, reduced mod 1 (exact-fma split of t*rev)
    float p = tf * hi;
    float e = fmaf(tf, hi, -p);                 // exact rounding error of p
    float f = (p - floorf(p)) + fmaf(tf, lo, e);
    f -= floorf(f);

    const float c0 = cos_rev(f);
    const float s0 = sin_rev(f);
    const float e0 = __expf(xr * tf);

    // y = w * state(t)  (dt already folded into w)
    float yr = e0 * fmaf(wr, c0, -(wi * s0));
    float yi = e0 * fmaf(wr, s0,   wi * c0);

    #pragma unroll
    for (int j = 0; j < CHUNK; ++j) {
      acc[j] += yr;
      const float nyr = fmaf(yr, str, -(yi * sti));
      yi = fmaf(yr, sti, yi * str);
      yr = nyr;
    }
  }

  float* op = out + d * SEQ_LEN + t;
  #pragma unroll
  for (int j = 0; j < CHUNK; ++j) op[j * TPD] = acc[j];
}

extern "C" void kernel_launch(void* const* d_in, const int* in_sizes, int n_in,
                              void* d_out, int out_size, void* d_ws, size_t ws_size,
                              hipStream_t stream) {
  const float* A_real = (const float*)d_in[0];
  const float* A_imag = (const float*)d_in[1];
  const float* C      = (const float*)d_in[2];
  const float* log_dt = (const float*)d_in[3];
  const float* B      = (const float*)d_in[4];
  // d_in[5] is L (== SEQ_LEN), compile-time constant here.
  float* out = (float*)d_out;

  dim3 grid(D_MODEL / DPB);
  dim3 block(BLOCK);
  s4d_kernel<<<grid, block, 0, stream>>>(A_real, A_imag, C, log_dt, B, out);
}

// Round 2
// 72.356 us; speedup vs baseline: 1.0915x; 1.0915x over previous
//
#include <hip/hip_runtime.h>
#include <math.h>

// S4D kernel materialization:
//   out[d,l] = dt_d * sum_n Re{ (Cr + i Ci) * B * exp(dt_d * (Ar + i Ai) * l) }
// D=1024, N=64, L=1024, fp32.
//
// R2 design:
//  - One block per d (1024 blocks, 256 thr -> 16 waves/CU vs R1's 8).
//  - NO transcendentals in the main loop: per-(d,n) LDS tables
//      hiT[n][k] = exp(dtA*16k) (k<8), loT[n][m] = exp(dtA*m) (m<16)
//    give state(t) = hiT[t>>4] * loT[t&15] in one complex mul.
//    Reads are broadcast / exactly-32-bank patterns (conflict-free).
//  - n split across half-blocks (32 n's/thread), LDS reduction at end.
//  - l-chunk recurrence (l = t + 128*j, j<8) as a 3-term REAL recurrence:
//      u_{j+1} = 2*Re(r)*u_j - |r|^2*u_{j-1},  r = exp(dtA*128)
//    (3 ops per (n,j) instead of 5 for the complex rotation).

#define D_MODEL 1024
#define N_STATE 64
#define SEQ_LEN 1024
#define CHUNK   8
#define TPD     128                 // threads covering t (l = t + 128*j)
#define NSPLIT  2
#define NPT     (N_STATE / NSPLIT)  // 32 n's per thread
#define BLOCK   (TPD * NSPLIT)      // 256

#define INV_2PI 0.15915494309189535

__device__ __forceinline__ float sin_rev(float f) { return __builtin_amdgcn_sinf(f); }
__device__ __forceinline__ float cos_rev(float f) { return __builtin_amdgcn_cosf(f); }

__global__ __launch_bounds__(BLOCK, 4) void s4d_kernel(
    const float* __restrict__ A_real, const float* __restrict__ A_imag,
    const float* __restrict__ C, const float* __restrict__ log_dt,
    const float* __restrict__ B, float* __restrict__ out)
{
  __shared__ float2 hiT[N_STATE][8];    // exp(dtA*16k)        4 KB
  __shared__ float2 loT[N_STATE][16];   // exp(dtA*m)          8 KB
  __shared__ float4 ws[N_STATE];        // {wr, wi, str, sti}  1 KB
  __shared__ float  red[CHUNK][TPD];    // n-split reduction   4 KB

  const int tid = threadIdx.x;
  const int d   = blockIdx.x;
  const float dt = __expf(log_dt[d]);

  // ---- build tables: 64n x 24 entries = 1536, 6 per thread ----
  #pragma unroll
  for (int i = 0; i < 6; ++i) {
    const int e   = tid + BLOCK * i;          // < 1536
    const int n   = e / 24;
    const int idx = e - n * 24;
    const int steps = (idx < 8) ? (idx << 4) : (idx - 8);
    const float ar = A_real[d * N_STATE + n];
    const float ai = A_imag[d * N_STATE + n];
    const float xr = dt * ar;
    const double drev = (double)dt * (double)ai * INV_2PI;  // rev per unit l
    const double ph = drev * (double)steps;
    const float  fr = (float)(ph - floor(ph));
    const float mag = __expf(xr * (float)steps);
    const float2 v = make_float2(mag * cos_rev(fr), mag * sin_rev(fr));
    if (idx < 8) hiT[n][idx] = v; else loT[n][idx - 8] = v;
  }
  if (tid < N_STATE) {
    const int n = tid;
    const float ar = A_real[d * N_STATE + n];
    const float ai = A_imag[d * N_STATE + n];
    const float b  = B[d * N_STATE + n];
    const float cr = C[(d * N_STATE + n) * 2 + 0];
    const float ci = C[(d * N_STATE + n) * 2 + 1];
    const float xr = dt * ar;
    const double drev = (double)dt * (double)ai * INV_2PI;
    const double ph = drev * 128.0;
    const float  fr = (float)(ph - floor(ph));
    const float mag = __expf(xr * 128.0f);
    ws[n] = make_float4(cr * b * dt, ci * b * dt,
                        mag * cos_rev(fr), mag * sin_rev(fr));
  }
  __syncthreads();

  const int t     = tid & (TPD - 1);
  const int split = tid >> 7;
  const int thi   = t >> 4;
  const int tlo   = t & 15;

  float acc[CHUNK];
  #pragma unroll
  for (int j = 0; j < CHUNK; ++j) acc[j] = 0.0f;

  const int n0 = split * NPT;
  #pragma unroll 4
  for (int nn = 0; nn < NPT; ++nn) {
    const int n = n0 + nn;
    const float4 w4 = ws[n];
    const float2 h  = hiT[n][thi];
    const float2 l2 = loT[n][tlo];
    // state(t) = h * l2
    const float sr = fmaf(h.x, l2.x, -(h.y * l2.y));
    const float si = fmaf(h.x, l2.y,   h.y * l2.x);
    // y0 = w * state ; u_j = Re(y0 * r^j), r = {w4.z, w4.w}
    float u0 = fmaf(w4.x, sr, -(w4.y * si));
    const float yi = fmaf(w4.x, si, w4.y * sr);
    float u1 = fmaf(u0, w4.z, -(yi * w4.w));
    const float a2 = w4.z + w4.z;                       //  2*Re(r)
    const float nb = -fmaf(w4.z, w4.z, w4.w * w4.w);    // -|r|^2
    acc[0] += u0;
    acc[1] += u1;
    #pragma unroll
    for (int j = 2; j < CHUNK; ++j) {
      const float u2 = fmaf(a2, u1, nb * u0);
      acc[j] += u2;
      u0 = u1; u1 = u2;
    }
  }

  // ---- n-split reduction + store ----
  if (split == 1) {
    #pragma unroll
    for (int j = 0; j < CHUNK; ++j) red[j][t] = acc[j];
  }
  __syncthreads();
  if (split == 0) {
    float* op = out + d * SEQ_LEN + t;
    #pragma unroll
    for (int j = 0; j < CHUNK; ++j) op[j * TPD] = acc[j] + red[j][t];
  }
}

extern "C" void kernel_launch(void* const* d_in, const int* in_sizes, int n_in,
                              void* d_out, int out_size, void* d_ws, size_t ws_size,
                              hipStream_t stream) {
  const float* A_real = (const float*)d_in[0];
  const float* A_imag = (const float*)d_in[1];
  const float* C      = (const float*)d_in[2];
  const float* log_dt = (const float*)d_in[3];
  const float* B      = (const float*)d_in[4];
  float* out = (float*)d_out;

  s4d_kernel<<<dim3(D_MODEL), dim3(BLOCK), 0, stream>>>(
      A_real, A_imag, C, log_dt, B, out);
}